// Round 5
// baseline (206.897 us; speedup 1.0000x reference)
//
#include <hip/hip_runtime.h>

#define TC 128
#define KD 64
#define WLOG_MIN (-5.2983174f)   // ln(0.005)

typedef __attribute__((ext_vector_type(8))) short short8;
typedef __attribute__((ext_vector_type(4))) short short4_t;
typedef __attribute__((ext_vector_type(4))) float f32x4;

__device__ __forceinline__ unsigned short f2bf(float x) {
  union { float f; unsigned int u; } c; c.f = x;
  unsigned int u = c.u + 0x7fffu + ((c.u >> 16) & 1u);   // RNE
  return (unsigned short)(u >> 16);
}
__device__ __forceinline__ float bf2f(unsigned short x) {
  union { unsigned int u; float f; } c; c.u = ((unsigned int)x) << 16; return c.f;
}

// rd_s/ki_s swizzle: element (t,kd) stored at t*64 + (slot<<3 | kd&7),
// slot = (kd>>3) ^ (t&7) ^ ((t>>3)&7).  vT swizzle: slot = g ^ (row&7).
// sT (K2) swizzle: slot = (kd>>3) ^ (vd&7) ^ ((vd>>3)&7)  (row-pair bit mixed
// in so the scalar transpose scatter writes spread over all 32 banks).

// ---------------------------------------------------------------------------
// K1: per-(b,h,chunk). 54,272B LDS -> 3 blocks/CU. Two barriers.
//  r/k/v loads software-prefetched in groups of 8 (group 0 issued before the
//  pass-1 barrier - independent of the cumsum).
// ---------------------------------------------------------------------------
__global__ __launch_bounds__(256, 3)
void rwkv_intra_mfma(const float* __restrict__ rr, const float* __restrict__ kk_,
                     const float* __restrict__ vv, const float* __restrict__ ww,
                     const float* __restrict__ uu, float* __restrict__ out,
                     unsigned short* __restrict__ wkv_u16, float* __restrict__ wse_ws,
                     unsigned short* __restrict__ rw_u16, unsigned short* __restrict__ diag_u16,
                     int H, int N) {
  __shared__ alignas(16) unsigned short rd_s[TC * KD];
  __shared__ alignas(16) unsigned short ki_s[TC * KD];
  __shared__ alignas(16) unsigned short vT_s[KD * TC];
  __shared__ alignas(16) unsigned char su_raw[5120];   // union: segtot f32[4][64] | Ast u16[4][640]
  float* segtot = (float*)su_raw;
  unsigned short* Ast = (unsigned short*)su_raw;

  const int bid = blockIdx.x;
  const int n = bid % N, bh = bid / N, h = bh % H;
  const size_t base = ((size_t)bh * N + n) * (TC * KD);
  const float *rg = rr + base, *kg = kk_ + base, *vg = vv + base, *wg = ww + base;
  unsigned short* diagg = diag_u16 + (size_t)bid * TC;

  const int tid = threadIdx.x;
  const int lk = tid & 63;    // k-column during staging
  const int wv = tid >> 6;    // wave id = t-segment

  // ---- pass 1: w (regs) + segment totals; prefetch r/k/v group 0 ----
  float wl[32];
  {
    float c = 0.f;
    #pragma unroll
    for (int tt = 0; tt < 32; ++tt) {
      wl[tt] = fmaxf(wg[(wv * 32 + tt) * KD + lk], WLOG_MIN);
      c += wl[tt];
    }
    segtot[wv * 64 + lk] = c;
  }
  float rp[8], kp[8], vp[8];
  #pragma unroll
  for (int q = 0; q < 8; ++q) {
    const int t = wv * 32 + q;
    rp[q] = rg[t * KD + lk]; kp[q] = kg[t * KD + lk]; vp[q] = vg[t * KD + lk];
  }
  __syncthreads();
  const float s0 = segtot[0 * 64 + lk], s1 = segtot[1 * 64 + lk];
  const float s2 = segtot[2 * 64 + lk], s3 = segtot[3 * 64 + lk];
  const float myoff = s0 + s1;   // cum at t = Tc/2
  const float segofs = (wv == 0) ? 0.f : (wv == 1) ? s0 : (wv == 2) ? (s0 + s1) : (s0 + s1 + s2);
  const float wsum = s0 + s1 + s2 + s3;
  const float wsoff_own = __expf(wsum - myoff);   // reg (segtot clobbered by Ast)
  if (wv == 0) wse_ws[((size_t)bh * N + n) * KD + lk] = __expf(wsum);
  const float eoff = __expf(myoff);

  // ---- pass 2: staging (rotating 8-deep prefetch) ----
  {
    float c = segofs;
    const float uk = uu[h * KD + lk];
    unsigned short* rwg = rw_u16 + base;
    #pragma unroll
    for (int g8 = 0; g8 < 4; ++g8) {
      float rc8[8], kc8[8], vc8[8];
      #pragma unroll
      for (int q = 0; q < 8; ++q) { rc8[q] = rp[q]; kc8[q] = kp[q]; vc8[q] = vp[q]; }
      if (g8 < 3) {
        #pragma unroll
        for (int q = 0; q < 8; ++q) {
          const int t = wv * 32 + (g8 + 1) * 8 + q;
          rp[q] = rg[t * KD + lk]; kp[q] = kg[t * KD + lk]; vp[q] = vg[t * KD + lk];
        }
      }
      short8 vb8;
      float darr[8];
      #pragma unroll
      for (int q = 0; q < 8; ++q) {
        const int tt = g8 * 8 + q;
        const int t = wv * 32 + tt;
        float rv = rc8[q], kv = kc8[q], vvv = vc8[q];
        const int slot = (lk >> 3) ^ (t & 7) ^ ((t >> 3) & 7);
        const int nat = t * KD + (slot << 3) + (lk & 7);
        float e1 = __expf(c - myoff);
        rd_s[nat] = f2bf(rv * e1);
        rwg[t * KD + lk] = f2bf(rv * e1 * eoff);  // r * exp(cum) for K2
        ki_s[nat] = f2bf(kv * __expf(myoff - c - wl[tt]));
        vb8[q] = (short)f2bf(vvv);
        darr[q] = rv * uk * kv;
        c += wl[tt];
      }
      const int g = wv * 4 + g8;
      *(short8*)&vT_s[lk * TC + ((g ^ (lk & 7)) << 3)] = vb8;
      #pragma unroll
      for (int o = 32; o > 0; o >>= 1)
        #pragma unroll
        for (int q = 0; q < 8; ++q) darr[q] += __shfl_xor(darr[q], o, 64);
      if (lk == 0) {
        short8 dpk;
        #pragma unroll
        for (int q = 0; q < 8; ++q) dpk[q] = (short)f2bf(darr[q]);
        *(short8*)&diagg[g * 8] = dpk;
      }
    }
  }
  __syncthreads();

  const int lane = tid & 63, quad = lane >> 4, l16 = lane & 15;

  // ---- wkv = (ki * w_inter)^T @ v -> bf16 ws (A-frags via scalar LDS reads) ----
  {
    f32x4 acc[4] = {{0,0,0,0},{0,0,0,0},{0,0,0,0},{0,0,0,0}};
    const int kdg = wv * 2 + (l16 >> 3), kd7 = l16 & 7;
    #pragma unroll
    for (int ks = 0; ks < 4; ++ks) {
      short8 a;
      #pragma unroll
      for (int j = 0; j < 8; ++j) {
        const int t = ks * 32 + quad * 8 + j;
        a[j] = (short)ki_s[t * KD + (((kdg ^ (t & 7) ^ ((t >> 3) & 7)) << 3) + kd7)];
      }
      #pragma unroll
      for (int nn = 0; nn < 4; ++nn) {
        const int vd = nn * 16 + l16;
        short8 b = *(const short8*)&vT_s[vd * TC + (((ks * 4 + quad) ^ (vd & 7)) << 3)];
        acc[nn] = __builtin_amdgcn_mfma_f32_16x16x32_bf16(a, b, acc[nn], 0, 0, 0);
      }
    }
    float wso[4];
    #pragma unroll
    for (int reg = 0; reg < 4; ++reg) wso[reg] = __shfl(wsoff_own, wv * 16 + quad * 4 + reg, 64);
    unsigned short* wkvg = wkv_u16 + ((size_t)bh * N + n) * (KD * KD);
    #pragma unroll
    for (int nn = 0; nn < 4; ++nn)
      #pragma unroll
      for (int reg = 0; reg < 4; ++reg)
        wkvg[(wv * 16 + quad * 4 + reg) * KD + nn * 16 + l16] = f2bf(acc[nn][reg] * wso[reg]);
  }

  // ---- fused A^T tiles + out = A@v (per-wave, no block sync) ----
  #pragma unroll
  for (int half = 0; half < 2; ++half) {
    const int ib = half ? (7 - wv) : wv;
    const int i0 = ib * 16;
    const int irow = i0 + l16;
    const int rsw = (irow & 7) ^ ((irow >> 3) & 7);
    short8 b0 = *(const short8*)&rd_s[irow * KD + ((quad ^ rsw) << 3)];
    short8 b1 = *(const short8*)&rd_s[irow * KD + (((4 + quad) ^ rsw) << 3)];
    const float diag_i = bf2f(diagg[irow]);
    f32x4 oacc[4] = {{0,0,0,0},{0,0,0,0},{0,0,0,0},{0,0,0,0}};
    const int npairs = (ib + 2) >> 1;
    unsigned short* astw = Ast + wv * 640;
    for (int jp = 0; jp < npairs; ++jp) {
      #pragma unroll
      for (int jj = 0; jj < 2; ++jj) {
        const int j = jp * 2 + jj;
        short4_t pk;
        if (j <= ib) {
          const int jrow = j * 16 + l16;
          const int jsw = (jrow & 7) ^ ((jrow >> 3) & 7);
          short8 a0 = *(const short8*)&ki_s[jrow * KD + ((quad ^ jsw) << 3)];
          short8 a1 = *(const short8*)&ki_s[jrow * KD + (((4 + quad) ^ jsw) << 3)];
          f32x4 at = {0, 0, 0, 0};
          at = __builtin_amdgcn_mfma_f32_16x16x32_bf16(a0, b0, at, 0, 0, 0);
          at = __builtin_amdgcn_mfma_f32_16x16x32_bf16(a1, b1, at, 0, 0, 0);
          #pragma unroll
          for (int reg = 0; reg < 4; ++reg) {
            const int je = j * 16 + quad * 4 + reg;
            float val = at[reg];
            if (j == ib) val = (je < irow) ? val : ((je == irow) ? diag_i : 0.f);
            pk[reg] = (short)f2bf(val);
          }
        } else {
          pk = (short4_t)0;  // guard half for even ib
        }
        *(short4_t*)&astw[l16 * 40 + jj * 16 + quad * 4] = pk;
      }
      short8 af = *(const short8*)&astw[l16 * 40 + quad * 8];
      #pragma unroll
      for (int nn = 0; nn < 4; ++nn) {
        const int vd = nn * 16 + l16;
        short8 bv = *(const short8*)&vT_s[vd * TC + (((jp * 4 + quad) ^ (vd & 7)) << 3)];
        oacc[nn] = __builtin_amdgcn_mfma_f32_16x16x32_bf16(af, bv, oacc[nn], 0, 0, 0);
      }
    }
    float* og = out + base;
    #pragma unroll
    for (int nn = 0; nn < 4; ++nn)
      #pragma unroll
      for (int reg = 0; reg < 4; ++reg)
        og[(i0 + quad * 4 + reg) * KD + nn * 16 + l16] = oacc[nn][reg];
  }
}

// ---------------------------------------------------------------------------
// K2: per-(b,h,chunk) block (1024 blocks). Inline redundant scan: rebuild
// S_n = sum_{m<n} (prod wse) wkv_m + (prod wse) st0 by a backward sweep over
// predecessor chunks (L2/L3-resident), LDS-transpose S, then
// out += rw @ S via MFMA (A-frags straight from global). Block n=N-1 also
// writes the final state. 8.2KB LDS -> ~8 blocks/CU.
// ---------------------------------------------------------------------------
__global__ __launch_bounds__(256)
void rwkv_state_inter(const unsigned short* __restrict__ wkv_u16,
                      const float* __restrict__ wse_ws,
                      const float* __restrict__ st_in,
                      const unsigned short* __restrict__ rw_u16,
                      float* __restrict__ out, float* __restrict__ final_out, int N) {
  __shared__ alignas(16) unsigned short sT[KD * KD];  // [vd][kd] swizzled
  const int bid = blockIdx.x;
  const int n = bid % N, bh = bid / N;
  const int tid = threadIdx.x;
  const int kd1 = tid >> 3;          // 0..31
  const int kd2 = kd1 + 32;
  const int v0 = (tid & 7) * 8;
  const size_t cbase = (size_t)bh * N;

  float S1[8], S2[8];
  float P1 = 1.f, P2 = 1.f;
  #pragma unroll
  for (int j = 0; j < 8; ++j) { S1[j] = 0.f; S2[j] = 0.f; }
  for (int m = n - 1; m >= 0; --m) {
    const unsigned short* wk = wkv_u16 + (cbase + m) * (KD * KD);
    short8 a1 = *(const short8*)&wk[kd1 * KD + v0];
    short8 a2 = *(const short8*)&wk[kd2 * KD + v0];
    float e1 = wse_ws[(cbase + m) * KD + kd1];
    float e2 = wse_ws[(cbase + m) * KD + kd2];
    #pragma unroll
    for (int j = 0; j < 8; ++j) {
      S1[j] += P1 * bf2f((unsigned short)a1[j]);
      S2[j] += P2 * bf2f((unsigned short)a2[j]);
    }
    P1 *= e1; P2 *= e2;
  }
  {
    const float* s0g = st_in + (size_t)bh * (KD * KD);
    #pragma unroll
    for (int j = 0; j < 8; ++j) {
      S1[j] += P1 * s0g[kd1 * KD + v0 + j];
      S2[j] += P2 * s0g[kd2 * KD + v0 + j];
    }
  }
  if (n == N - 1) {  // final state output
    const unsigned short* wk = wkv_u16 + (cbase + N - 1) * (KD * KD);
    short8 a1 = *(const short8*)&wk[kd1 * KD + v0];
    short8 a2 = *(const short8*)&wk[kd2 * KD + v0];
    float e1 = wse_ws[(cbase + N - 1) * KD + kd1];
    float e2 = wse_ws[(cbase + N - 1) * KD + kd2];
    float* fo = final_out + (size_t)bh * (KD * KD);
    #pragma unroll
    for (int j = 0; j < 8; ++j) {
      fo[kd1 * KD + v0 + j] = S1[j] * e1 + bf2f((unsigned short)a1[j]);
      fo[kd2 * KD + v0 + j] = S2[j] * e2 + bf2f((unsigned short)a2[j]);
    }
  }
  // LDS transpose: sT[vd][kd], slot = (kd>>3) ^ (vd&7) ^ ((vd>>3)&7)
  #pragma unroll
  for (int j = 0; j < 8; ++j) {
    const int vd = v0 + j;
    const int rs = (vd & 7) ^ ((vd >> 3) & 7);
    sT[vd * KD + ((((kd1 >> 3) ^ rs) << 3) | (kd1 & 7))] = f2bf(S1[j]);
    sT[vd * KD + ((((kd2 >> 3) ^ rs) << 3) | (kd2 & 7))] = f2bf(S2[j]);
  }
  __syncthreads();

  const int lane = tid & 63, wvv = tid >> 6, quad = lane >> 4, l16 = lane & 15;
  const unsigned short* rwg = rw_u16 + (cbase + n) * (TC * KD);
  float* og = out + (cbase + n) * (TC * KD);
  #pragma unroll
  for (int half = 0; half < 2; ++half) {
    const int mt = wvv + half * 4;
    const int trow = mt * 16 + l16;
    short8 a0 = *(const short8*)&rwg[trow * KD + quad * 8];
    short8 a1 = *(const short8*)&rwg[trow * KD + 32 + quad * 8];
    f32x4 acc[4] = {{0,0,0,0},{0,0,0,0},{0,0,0,0},{0,0,0,0}};
    #pragma unroll
    for (int nn = 0; nn < 4; ++nn) {
      const int vd = nn * 16 + l16;
      const int rs = (vd & 7) ^ ((vd >> 3) & 7);
      short8 b0 = *(const short8*)&sT[vd * KD + ((quad ^ rs) << 3)];
      short8 b1 = *(const short8*)&sT[vd * KD + (((4 + quad) ^ rs) << 3)];
      acc[nn] = __builtin_amdgcn_mfma_f32_16x16x32_bf16(a0, b0, acc[nn], 0, 0, 0);
      acc[nn] = __builtin_amdgcn_mfma_f32_16x16x32_bf16(a1, b1, acc[nn], 0, 0, 0);
    }
    #pragma unroll
    for (int nn = 0; nn < 4; ++nn)
      #pragma unroll
      for (int reg = 0; reg < 4; ++reg)
        og[(size_t)(mt * 16 + quad * 4 + reg) * KD + nn * 16 + l16] += acc[nn][reg];
  }
}

// ---------------------------------------------------------------------------
// Workspace (~24.5 MB): [wkv u16: BH*N*K*K][wse f32: BH*N*K]
//                       [rw u16: BH*T*K][diag u16: BH*N*TC]
// ---------------------------------------------------------------------------
extern "C" void kernel_launch(void* const* d_in, const int* in_sizes, int n_in,
                              void* d_out, int out_size, void* d_ws, size_t ws_size,
                              hipStream_t stream) {
  const float* r = (const float*)d_in[0];
  const float* k = (const float*)d_in[1];
  const float* v = (const float*)d_in[2];
  const float* w = (const float*)d_in[3];
  const float* u = (const float*)d_in[4];
  const float* st0 = (const float*)d_in[5];
  float* out = (float*)d_out;

  const int BH = in_sizes[5] / (KD * KD);  // 64
  const int H = in_sizes[4] / KD;          // 16
  const int T = in_sizes[0] / (BH * KD);   // 2048
  const int N = T / TC;                    // 16

  unsigned short* wkv_u16 = (unsigned short*)d_ws;
  float* wse_ws = (float*)(wkv_u16 + (size_t)BH * N * KD * KD);
  unsigned short* rw_u16 = (unsigned short*)(wse_ws + (size_t)BH * N * KD);
  unsigned short* diag_u16 = rw_u16 + (size_t)BH * T * KD;
  float* final_out = out + (size_t)in_sizes[0];

  rwkv_intra_mfma<<<BH * N, 256, 0, stream>>>(r, k, v, w, u, out, wkv_u16, wse_ws,
                                              rw_u16, diag_u16, H, N);
  rwkv_state_inter<<<BH * N, 256, 0, stream>>>(wkv_u16, wse_ws, st0, rw_u16,
                                               out, final_out, N);
}